// Round 7
// baseline (262.767 us; speedup 1.0000x reference)
//
#include <hip/hip_runtime.h>

#define DEPTH 25
#define DIM   64
#define HID   100

typedef _Float16 f16x4 __attribute__((ext_vector_type(4)));
typedef _Float16 f16x8 __attribute__((ext_vector_type(8)));
typedef __fp16   h2    __attribute__((ext_vector_type(2)));   // cvt_pkrtz result type
typedef float    f32x4 __attribute__((ext_vector_type(4)));
typedef float    f32x2 __attribute__((ext_vector_type(2)));

// ---- Prep kernel: Levy noise + fragment-ordered f16 weights, ONCE ----
// wpre halves: [0,4096) W_down frags | [4096,8192) dt*W_drift frags |
//              [8192,15360) W1 frags (n>=100 zero-padded).
// Fragment fi: lane l holds halves [fi*512 + l*8, +8).
__global__ __launch_bounds__(256) void prep_kernel(
    const float* __restrict__ u_raw,  const float* __restrict__ w_raw,
    const float* __restrict__ W_down, const float* __restrict__ W_drift,
    const float* __restrict__ W1,     const float* __restrict__ b1,
    const float* __restrict__ W2,
    float* __restrict__ noise, _Float16* __restrict__ wpre,
    float* __restrict__ b1p, float* __restrict__ w2p)
{
    const int idx = blockIdx.x * 256 + threadIdx.x;
    if (idx < DEPTH * DIM) {
        float u = u_raw[idx];
        float w = w_raw[idx];
        float U  = 3.14159265358979323846f * (u - 0.5f);
        float Wv = -logf(fminf(fmaxf(w, 1e-12f), 1.0f));
        float t1 = sinf(1.8f * U) / powf(cosf(U), 0.5555555555555556f);
        float ratio = cosf(0.8f * U) / fmaxf(Wv, 1e-12f);
        float X = t1 * powf(ratio, -0.4444444444444444f);
        noise[idx] = fminf(fmaxf(0.1f * X, -10.0f), 10.0f);
    } else if (idx < 1600 + 7680) {
        const int p = idx - 1600;              // h2-pair index
        int rel, kind;
        if (p < 2048)      { kind = 0; rel = p; }
        else if (p < 4096) { kind = 1; rel = p - 2048; }
        else               { kind = 2; rel = p - 4096; }
        const int fi    = rel >> 8;
        const int lane2 = (rel >> 2) & 63;
        const int j     = (rel & 3) * 2;
        const int m     = (fi >> 1) * 16 + (lane2 & 15);
        const int k     = (fi & 1) * 32 + ((j & 4) ? 16 : 0)
                        + (lane2 >> 4) * 4 + (j & 3);
        float v0, v1;
        if (kind == 0) {
            v0 = W_down[k * DIM + m];           v1 = W_down[(k + 1) * DIM + m];
        } else if (kind == 1) {
            v0 = 0.04f * W_drift[k * DIM + m];  v1 = 0.04f * W_drift[(k + 1) * DIM + m];
        } else {
            v0 = (m < HID) ? W1[k * HID + m] : 0.0f;
            v1 = (m < HID) ? W1[(k + 1) * HID + m] : 0.0f;
        }
        *(h2*)(wpre + p * 2) = __builtin_amdgcn_cvt_pkrtz(v0, v1);
    } else if (idx < 9280 + 112) {
        const int i = idx - 9280;
        b1p[i] = (i < HID) ? b1[i] : 0.0f;      // padded to 112
    } else if (idx < 9392 + 112) {
        const int i = idx - 9392;
        w2p[i] = (i < HID) ? W2[i] : 0.0f;      // padded to 112
    }
}

union frag_u { h2 p[4]; f16x8 v; };

// ================= PRE path: 16 rows/wave, barrier-free, 5 blk/CU =================
// Round-7 theory: wall = scheduling bubbles from few (2-3) phase-aligned
// waves/SIMD. Changes vs round 5:
//  * NO __syncthreads: noise staged PER-WAVE (own LDS region) -> waves desync,
//    MFMA/VALU bursts decorrelate across waves.
//  * pair-wise step processing (Mt pairs 0,1 then 2,3) + double-buffered
//    bfrag -> transient regs halved; __launch_bounds__(256,5) -> ~5 waves/SIMD.
//  * s_setprio(1) around MFMA clusters (pays only with desynced waves - T5).
// mfma_f32_16x16x32_f16 stacked-halves K layout (VERIFIED round 2).
__global__ __launch_bounds__(256, 5) void sdenet_fused_pre3(
    const float* __restrict__ x,      const float* __restrict__ noise_g,
    const _Float16* __restrict__ wpre,
    const float* __restrict__ b_down, const float* __restrict__ b_drift,
    const float* __restrict__ b1p,    const float* __restrict__ w2p,
    const float* __restrict__ b2,
    float* __restrict__ out, int batch)
{
    __shared__ float noise_lds[4 * DEPTH * DIM];   // 25600 B, one region per wave

    const int tid  = threadIdx.x;
    const int wave = tid >> 6;
    const int lane = tid & 63;
    const int r    = lane & 15;        // batch row within wave tile (B/C col)
    const int g    = lane >> 4;        // 16-lane group 0..3
    const int row  = blockIdx.x * 64 + wave * 16 + r;
    const int fbase = lane * 8;        // per-lane fragment offset (halves)
    const float dt = 0.04f;

    // ---- per-wave noise staging (no block barrier anywhere) ----
    float* nbase = noise_lds + wave * (DEPTH * DIM);
    {
        const float4* src = (const float4*)noise_g;
        float4* dst = (float4*)nbase;
        #pragma unroll
        for (int it = 0; it < 7; ++it) {
            const int idx = lane + it * 64;
            if (idx < DEPTH * DIM / 4) dst[idx] = src[idx];
        }
    }

    // prefetch x (overlaps the LDS-write drain; same-wave deps only)
    float4 xv[4];
    #pragma unroll
    for (int kt = 0; kt < 2; ++kt) {
        xv[2*kt]   = *(const float4*)(x + row * DIM + kt * 32 + g * 4);
        xv[2*kt+1] = *(const float4*)(x + row * DIM + kt * 32 + 16 + g * 4);
    }

    f16x8 bfrag[2];
    #pragma unroll
    for (int kt = 0; kt < 2; ++kt) {
        frag_u u;
        u.p[0] = __builtin_amdgcn_cvt_pkrtz(xv[2*kt].x,   xv[2*kt].y);
        u.p[1] = __builtin_amdgcn_cvt_pkrtz(xv[2*kt].z,   xv[2*kt].w);
        u.p[2] = __builtin_amdgcn_cvt_pkrtz(xv[2*kt+1].x, xv[2*kt+1].y);
        u.p[3] = __builtin_amdgcn_cvt_pkrtz(xv[2*kt+1].z, xv[2*kt+1].w);
        bfrag[kt] = u.v;
    }

    // ---------- initial: out0^T = W_down^T @ x^T + b_down ----------
    f32x2 out2[4][2];   // master fp32 state, C/D layout (dim = Mt*16 + 4g + reg)
    #pragma unroll
    for (int Mt = 0; Mt < 4; ++Mt) {
        f32x4 acc = *(const f32x4*)(b_down + Mt * 16 + g * 4);
        #pragma unroll
        for (int kt = 0; kt < 2; ++kt)
            acc = __builtin_amdgcn_mfma_f32_16x16x32_f16(
                *(const f16x8*)(wpre + (Mt * 2 + kt) * 512 + fbase),
                bfrag[kt], acc, 0, 0, 0);
        out2[Mt][0][0] = acc[0]; out2[Mt][0][1] = acc[1];
        out2[Mt][1][0] = acc[2]; out2[Mt][1][1] = acc[3];
    }

    #pragma unroll
    for (int kt = 0; kt < 2; ++kt) {
        frag_u u;
        u.p[0] = __builtin_amdgcn_cvt_pkrtz(out2[2*kt  ][0][0], out2[2*kt  ][0][1]);
        u.p[1] = __builtin_amdgcn_cvt_pkrtz(out2[2*kt  ][1][0], out2[2*kt  ][1][1]);
        u.p[2] = __builtin_amdgcn_cvt_pkrtz(out2[2*kt+1][0][0], out2[2*kt+1][0][1]);
        u.p[3] = __builtin_amdgcn_cvt_pkrtz(out2[2*kt+1][1][0], out2[2*kt+1][1][1]);
        bfrag[kt] = u.v;
    }

    // ---------- head: logit = relu(out0@W1+b1)@W2 + b2 (padded, no masks) ----------
    const _Float16* w1pre = wpre + 8192;
    float partial = 0.0f;
    #pragma unroll
    for (int Mt = 0; Mt < 7; ++Mt) {          // HID padded 100 -> 112
        f32x4 acc = *(const f32x4*)(b1p + Mt * 16 + g * 4);
        #pragma unroll
        for (int kt = 0; kt < 2; ++kt)
            acc = __builtin_amdgcn_mfma_f32_16x16x32_f16(
                *(const f16x8*)(w1pre + (Mt * 2 + kt) * 512 + fbase),
                bfrag[kt], acc, 0, 0, 0);
        #pragma unroll
        for (int reg = 0; reg < 4; ++reg)
            partial += fmaxf(acc[reg], 0.0f) * w2p[Mt * 16 + g * 4 + reg];
    }
    partial += __shfl_xor(partial, 16);
    partial += __shfl_xor(partial, 32);
    const float logit = partial + b2[0];
    const float scale = 0.5f * (1.0f / (1.0f + expf(-logit)))
                      * powf(0.04f, 1.0f / 1.8f);
    const f32x2 scale2 = { scale, scale };
    const f32x2 c104   = { 1.04f, 1.04f };
    const f32x2 zero2  = { 0.0f, 0.0f };

    // ---------- persistent dt-scaled drift fragments + dt*bias (registers) ----------
    f16x8 aWd[4][2];
    #pragma unroll
    for (int Mt = 0; Mt < 4; ++Mt)
        #pragma unroll
        for (int kt = 0; kt < 2; ++kt)
            aWd[Mt][kt] = *(const f16x8*)(wpre + 4096 + (Mt * 2 + kt) * 512 + fbase);

    f32x4 biasd[4];
    #pragma unroll
    for (int Mt = 0; Mt < 4; ++Mt) {
        f32x4 b = *(const f32x4*)(b_drift + Mt * 16 + g * 4);
        biasd[Mt][0] = b[0] * dt; biasd[Mt][1] = b[1] * dt;
        biasd[Mt][2] = b[2] * dt; biasd[Mt][3] = b[3] * dt;
    }

    // ---------- 25 SDE steps, pair-wise (Mt 0,1 then 2,3) ----------
    #pragma unroll
    for (int t = 0; t < DEPTH; ++t) {
        f16x8 nb[2];
        #pragma unroll
        for (int p = 0; p < 2; ++p) {
            const int M0 = 2 * p, M1 = 2 * p + 1;
            const f32x4 nz0 = *(const f32x4*)(nbase + t * DIM + M0 * 16 + g * 4);
            const f32x4 nz1 = *(const f32x4*)(nbase + t * DIM + M1 * 16 + g * 4);

            __builtin_amdgcn_s_setprio(1);
            f32x4 a0 = __builtin_amdgcn_mfma_f32_16x16x32_f16(
                aWd[M0][0], bfrag[0], biasd[M0], 0, 0, 0);
            a0 = __builtin_amdgcn_mfma_f32_16x16x32_f16(
                aWd[M0][1], bfrag[1], a0, 0, 0, 0);
            f32x4 a1 = __builtin_amdgcn_mfma_f32_16x16x32_f16(
                aWd[M1][0], bfrag[0], biasd[M1], 0, 0, 0);
            a1 = __builtin_amdgcn_mfma_f32_16x16x32_f16(
                aWd[M1][1], bfrag[1], a1, 0, 0, 0);
            __builtin_amdgcn_s_setprio(0);

            // out = fma(scale, nz, fma(out, 1.04, relu(acc)))   [packed f32]
            #pragma unroll
            for (int h = 0; h < 2; ++h) {
                f32x2 a2 = { a0[2*h], a0[2*h+1] };
                f32x2 n2 = { nz0[2*h], nz0[2*h+1] };
                f32x2 rel = __builtin_elementwise_max(a2, zero2);
                f32x2 tmp = __builtin_elementwise_fma(out2[M0][h], c104, rel);
                out2[M0][h] = __builtin_elementwise_fma(scale2, n2, tmp);
            }
            #pragma unroll
            for (int h = 0; h < 2; ++h) {
                f32x2 a2 = { a1[2*h], a1[2*h+1] };
                f32x2 n2 = { nz1[2*h], nz1[2*h+1] };
                f32x2 rel = __builtin_elementwise_max(a2, zero2);
                f32x2 tmp = __builtin_elementwise_fma(out2[M1][h], c104, rel);
                out2[M1][h] = __builtin_elementwise_fma(scale2, n2, tmp);
            }
            frag_u u;
            u.p[0] = __builtin_amdgcn_cvt_pkrtz(out2[M0][0][0], out2[M0][0][1]);
            u.p[1] = __builtin_amdgcn_cvt_pkrtz(out2[M0][1][0], out2[M0][1][1]);
            u.p[2] = __builtin_amdgcn_cvt_pkrtz(out2[M1][0][0], out2[M1][0][1]);
            u.p[3] = __builtin_amdgcn_cvt_pkrtz(out2[M1][1][0], out2[M1][1][1]);
            nb[p] = u.v;
        }
        bfrag[0] = nb[0];
        bfrag[1] = nb[1];
    }

    // ---- final drift (undo dt scaling: relu(z) = relu(dt*z)*25) + stores ----
    const long long out2_off = (long long)batch * DIM;
    #pragma unroll
    for (int Mt = 0; Mt < 4; ++Mt) {
        f32x4 acc = __builtin_amdgcn_mfma_f32_16x16x32_f16(
            aWd[Mt][0], bfrag[0], biasd[Mt], 0, 0, 0);
        acc = __builtin_amdgcn_mfma_f32_16x16x32_f16(
            aWd[Mt][1], bfrag[1], acc, 0, 0, 0);
        float o0 = out2[Mt][0][0], o1 = out2[Mt][0][1];
        float o2 = out2[Mt][1][0], o3 = out2[Mt][1][1];
        float4 dv, ov;
        dv.x = fmaf(fmaxf(acc[0], 0.0f), 25.0f, o0);
        dv.y = fmaf(fmaxf(acc[1], 0.0f), 25.0f, o1);
        dv.z = fmaf(fmaxf(acc[2], 0.0f), 25.0f, o2);
        dv.w = fmaf(fmaxf(acc[3], 0.0f), 25.0f, o3);
        ov.x = o0; ov.y = o1; ov.z = o2; ov.w = o3;
        *(float4*)(out + (long long)row * DIM + Mt * 16 + g * 4) = dv;
        *(float4*)(out + out2_off + (long long)row * DIM + Mt * 16 + g * 4) = ov;
    }
}

// ============== FALLBACK path (round-4 kernel, in-block staging) ==============
__global__ __launch_bounds__(256, 4) void sdenet_fused_fb(
    const float* __restrict__ x,      const float* __restrict__ noise_g,
    const float* __restrict__ W_down, const float* __restrict__ b_down,
    const float* __restrict__ W_drift,const float* __restrict__ b_drift,
    const float* __restrict__ W1,     const float* __restrict__ b1,
    const float* __restrict__ W2,     const float* __restrict__ b2,
    float* __restrict__ out, int batch)
{
    __shared__ float    noise_lds[DEPTH * DIM];
    __shared__ float    bias_lds[DIM];
    __shared__ _Float16 wdown[4096];
    __shared__ _Float16 wdrift[4096];
    __shared__ _Float16 w1buf[7168];

    const int tid  = threadIdx.x;
    const int wave = tid >> 6;
    const int lane = tid & 63;
    const int r    = lane & 15;
    const int g    = lane >> 4;
    const int row  = blockIdx.x * 64 + wave * 16 + r;
    const int fbase = lane * 8;
    const float dt = 0.04f;

    {
        const float4* src = (const float4*)noise_g;
        float4* dst = (float4*)noise_lds;
        #pragma unroll
        for (int it = 0; it < 2; ++it) {
            int idx = tid + it * 256;
            if (idx < DEPTH * DIM / 4) dst[idx] = src[idx];
        }
    }
    if (tid < DIM) bias_lds[tid] = dt * b_drift[tid];

    for (int idx2 = tid; idx2 < 2048; idx2 += 256) {
        const int fi    = idx2 >> 8;
        const int lane2 = (idx2 >> 2) & 63;
        const int j     = (idx2 & 3) * 2;
        const int m     = (fi >> 1) * 16 + (lane2 & 15);
        const int k     = (fi & 1) * 32 + ((j & 4) ? 16 : 0)
                        + (lane2 >> 4) * 4 + (j & 3);
        *(h2*)(wdown + idx2 * 2) =
            __builtin_amdgcn_cvt_pkrtz(W_down[k * DIM + m],
                                       W_down[(k + 1) * DIM + m]);
        *(h2*)(wdrift + idx2 * 2) =
            __builtin_amdgcn_cvt_pkrtz(dt * W_drift[k * DIM + m],
                                       dt * W_drift[(k + 1) * DIM + m]);
    }
    for (int idx2 = tid; idx2 < 3584; idx2 += 256) {
        const int fi    = idx2 >> 8;
        const int lane2 = (idx2 >> 2) & 63;
        const int j     = (idx2 & 3) * 2;
        const int n     = (fi >> 1) * 16 + (lane2 & 15);
        const int k     = (fi & 1) * 32 + ((j & 4) ? 16 : 0)
                        + (lane2 >> 4) * 4 + (j & 3);
        const float v0 = (n < HID) ? W1[k * HID + n] : 0.0f;
        const float v1 = (n < HID) ? W1[(k + 1) * HID + n] : 0.0f;
        *(h2*)(w1buf + idx2 * 2) = __builtin_amdgcn_cvt_pkrtz(v0, v1);
    }

    float4 xlo[2], xhi[2];
    #pragma unroll
    for (int kt = 0; kt < 2; ++kt) {
        xlo[kt] = *(const float4*)(x + row * DIM + kt * 32 + g * 4);
        xhi[kt] = *(const float4*)(x + row * DIM + kt * 32 + 16 + g * 4);
    }
    __syncthreads();

    f16x8 bfrag[2];
    #pragma unroll
    for (int kt = 0; kt < 2; ++kt) {
        frag_u u;
        u.p[0] = __builtin_amdgcn_cvt_pkrtz(xlo[kt].x, xlo[kt].y);
        u.p[1] = __builtin_amdgcn_cvt_pkrtz(xlo[kt].z, xlo[kt].w);
        u.p[2] = __builtin_amdgcn_cvt_pkrtz(xhi[kt].x, xhi[kt].y);
        u.p[3] = __builtin_amdgcn_cvt_pkrtz(xhi[kt].z, xhi[kt].w);
        bfrag[kt] = u.v;
    }

    f32x2 out2[4][2];
    #pragma unroll
    for (int Mt = 0; Mt < 4; ++Mt) {
        f32x4 acc = *(const f32x4*)(b_down + Mt * 16 + g * 4);
        #pragma unroll
        for (int kt = 0; kt < 2; ++kt)
            acc = __builtin_amdgcn_mfma_f32_16x16x32_f16(
                *(const f16x8*)(wdown + (Mt * 2 + kt) * 512 + fbase),
                bfrag[kt], acc, 0, 0, 0);
        out2[Mt][0][0] = acc[0]; out2[Mt][0][1] = acc[1];
        out2[Mt][1][0] = acc[2]; out2[Mt][1][1] = acc[3];
    }

    auto refresh = [&]() {
        #pragma unroll
        for (int kt = 0; kt < 2; ++kt) {
            frag_u u;
            u.p[0] = __builtin_amdgcn_cvt_pkrtz(out2[2*kt  ][0][0], out2[2*kt  ][0][1]);
            u.p[1] = __builtin_amdgcn_cvt_pkrtz(out2[2*kt  ][1][0], out2[2*kt  ][1][1]);
            u.p[2] = __builtin_amdgcn_cvt_pkrtz(out2[2*kt+1][0][0], out2[2*kt+1][0][1]);
            u.p[3] = __builtin_amdgcn_cvt_pkrtz(out2[2*kt+1][1][0], out2[2*kt+1][1][1]);
            bfrag[kt] = u.v;
        }
    };
    refresh();

    float partial = 0.0f;
    #pragma unroll
    for (int Mt = 0; Mt < 7; ++Mt) {
        f32x4 acc;
        #pragma unroll
        for (int reg = 0; reg < 4; ++reg) {
            const int n = Mt * 16 + g * 4 + reg;
            acc[reg] = (n < HID) ? b1[n] : 0.0f;
        }
        #pragma unroll
        for (int kt = 0; kt < 2; ++kt)
            acc = __builtin_amdgcn_mfma_f32_16x16x32_f16(
                *(const f16x8*)(w1buf + (Mt * 2 + kt) * 512 + fbase),
                bfrag[kt], acc, 0, 0, 0);
        #pragma unroll
        for (int reg = 0; reg < 4; ++reg) {
            const int n = Mt * 16 + g * 4 + reg;
            if (n < HID) partial += fmaxf(acc[reg], 0.0f) * W2[n];
        }
    }
    partial += __shfl_xor(partial, 16);
    partial += __shfl_xor(partial, 32);
    const float logit = partial + b2[0];
    const float scale = 0.5f * (1.0f / (1.0f + expf(-logit)))
                      * powf(0.04f, 1.0f / 1.8f);
    const f32x2 scale2 = { scale, scale };
    const f32x2 c104   = { 1.04f, 1.04f };
    const f32x2 zero2  = { 0.0f, 0.0f };

    f16x8 aWd[4][2];
    #pragma unroll
    for (int Mt = 0; Mt < 4; ++Mt)
        #pragma unroll
        for (int kt = 0; kt < 2; ++kt)
            aWd[Mt][kt] = *(const f16x8*)(wdrift + (Mt * 2 + kt) * 512 + fbase);

    #pragma unroll
    for (int t = 0; t < DEPTH; ++t) {
        f32x4 nz[4];
        #pragma unroll
        for (int Mt = 0; Mt < 4; ++Mt)
            nz[Mt] = *(const f32x4*)(noise_lds + t * DIM + Mt * 16 + g * 4);

        f32x4 acc[4];
        #pragma unroll
        for (int Mt = 0; Mt < 4; ++Mt) {
            acc[Mt] = *(const f32x4*)(bias_lds + Mt * 16 + g * 4);
            acc[Mt] = __builtin_amdgcn_mfma_f32_16x16x32_f16(
                aWd[Mt][0], bfrag[0], acc[Mt], 0, 0, 0);
            acc[Mt] = __builtin_amdgcn_mfma_f32_16x16x32_f16(
                aWd[Mt][1], bfrag[1], acc[Mt], 0, 0, 0);
        }
        #pragma unroll
        for (int Mt = 0; Mt < 4; ++Mt) {
            #pragma unroll
            for (int h = 0; h < 2; ++h) {
                f32x2 a2 = { acc[Mt][2*h], acc[Mt][2*h+1] };
                f32x2 n2 = { nz[Mt][2*h],  nz[Mt][2*h+1] };
                f32x2 rel = __builtin_elementwise_max(a2, zero2);
                f32x2 tmp = __builtin_elementwise_fma(out2[Mt][h], c104, rel);
                out2[Mt][h] = __builtin_elementwise_fma(scale2, n2, tmp);
            }
        }
        refresh();
    }

    const long long out2_off = (long long)batch * DIM;
    #pragma unroll
    for (int Mt = 0; Mt < 4; ++Mt) {
        f32x4 acc = *(const f32x4*)(bias_lds + Mt * 16 + g * 4);
        acc = __builtin_amdgcn_mfma_f32_16x16x32_f16(
            aWd[Mt][0], bfrag[0], acc, 0, 0, 0);
        acc = __builtin_amdgcn_mfma_f32_16x16x32_f16(
            aWd[Mt][1], bfrag[1], acc, 0, 0, 0);
        float o0 = out2[Mt][0][0], o1 = out2[Mt][0][1];
        float o2 = out2[Mt][1][0], o3 = out2[Mt][1][1];
        float4 dv, ov;
        dv.x = fmaf(fmaxf(acc[0], 0.0f), 25.0f, o0);
        dv.y = fmaf(fmaxf(acc[1], 0.0f), 25.0f, o1);
        dv.z = fmaf(fmaxf(acc[2], 0.0f), 25.0f, o2);
        dv.w = fmaf(fmaxf(acc[3], 0.0f), 25.0f, o3);
        ov.x = o0; ov.y = o1; ov.z = o2; ov.w = o3;
        *(float4*)(out + (long long)row * DIM + Mt * 16 + g * 4) = dv;
        *(float4*)(out + out2_off + (long long)row * DIM + Mt * 16 + g * 4) = ov;
    }
}

extern "C" void kernel_launch(void* const* d_in, const int* in_sizes, int n_in,
                              void* d_out, int out_size, void* d_ws, size_t ws_size,
                              hipStream_t stream) {
    const float* x       = (const float*)d_in[0];
    const float* u_raw   = (const float*)d_in[1];
    const float* w_raw   = (const float*)d_in[2];
    const float* W_down  = (const float*)d_in[3];
    const float* b_down  = (const float*)d_in[4];
    const float* W_drift = (const float*)d_in[5];
    const float* b_drift = (const float*)d_in[6];
    const float* W1      = (const float*)d_in[7];
    const float* b1      = (const float*)d_in[8];
    const float* W2      = (const float*)d_in[9];
    const float* b2      = (const float*)d_in[10];
    float* out   = (float*)d_out;

    // workspace layout: [0,6400) noise f32 | [6400,37120) wpre f16 |
    //                   [37120,37568) b1p  | [37568,38016) w2p
    float*     noise = (float*)d_ws;
    _Float16*  wpre  = (_Float16*)((char*)d_ws + 6400);
    float*     b1p   = (float*)((char*)d_ws + 37120);
    float*     w2p   = (float*)((char*)d_ws + 37568);

    const int batch = in_sizes[0] / DIM;       // 262144

    if (ws_size >= 38016) {
        prep_kernel<<<38, 256, 0, stream>>>(u_raw, w_raw, W_down, W_drift,
                                            W1, b1, W2, noise, wpre, b1p, w2p);
        sdenet_fused_pre3<<<batch / 64, 256, 0, stream>>>(
            x, noise, wpre, b_down, b_drift, b1p, w2p, b2, out, batch);
    } else {
        prep_kernel<<<7, 256, 0, stream>>>(u_raw, w_raw, W_down, W_drift,
                                           W1, b1, W2, noise,
                                           (_Float16*)noise, noise, noise);
        sdenet_fused_fb<<<batch / 64, 256, 0, stream>>>(
            x, noise, W_down, b_down, W_drift, b_drift,
            W1, b1, W2, b2, out, batch);
    }
}

// Round 8
// 245.180 us; speedup vs baseline: 1.0717x; 1.0717x over previous
//
#include <hip/hip_runtime.h>

#define DEPTH 25
#define DIM   64
#define HID   100

typedef _Float16 f16x4 __attribute__((ext_vector_type(4)));
typedef _Float16 f16x8 __attribute__((ext_vector_type(8)));
typedef __fp16   h2    __attribute__((ext_vector_type(2)));   // cvt_pkrtz result type
typedef float    f32x4 __attribute__((ext_vector_type(4)));
typedef float    f32x2 __attribute__((ext_vector_type(2)));

// Packed FP32 FMA (VOP3P, gfx90a+): one instruction for 2 lanes-of-2.
// hipcc lowers __builtin_elementwise_fma(f32x2) to 2 scalar v_fma_f32;
// this emits v_pk_fma_f32 directly (round-8 lever: issue-bound kernel).
static __device__ __forceinline__ f32x2 pk_fma(f32x2 a, f32x2 b, f32x2 c) {
    f32x2 d;
    asm("v_pk_fma_f32 %0, %1, %2, %3" : "=v"(d) : "v"(a), "v"(b), "v"(c));
    return d;
}

// ---- Prep kernel: Levy noise + fragment-ordered f16 weights, ONCE ----
// wpre halves: [0,4096) W_down frags | [4096,8192) dt*W_drift frags |
//              [8192,15360) W1 frags (n>=100 zero-padded).
// Fragment fi: lane l holds halves [fi*512 + l*8, +8).
__global__ __launch_bounds__(256) void prep_kernel(
    const float* __restrict__ u_raw,  const float* __restrict__ w_raw,
    const float* __restrict__ W_down, const float* __restrict__ W_drift,
    const float* __restrict__ W1,     const float* __restrict__ b1,
    const float* __restrict__ W2,
    float* __restrict__ noise, _Float16* __restrict__ wpre,
    float* __restrict__ b1p, float* __restrict__ w2p)
{
    const int idx = blockIdx.x * 256 + threadIdx.x;
    if (idx < DEPTH * DIM) {
        float u = u_raw[idx];
        float w = w_raw[idx];
        float U  = 3.14159265358979323846f * (u - 0.5f);
        float Wv = -logf(fminf(fmaxf(w, 1e-12f), 1.0f));
        float t1 = sinf(1.8f * U) / powf(cosf(U), 0.5555555555555556f);
        float ratio = cosf(0.8f * U) / fmaxf(Wv, 1e-12f);
        float X = t1 * powf(ratio, -0.4444444444444444f);
        noise[idx] = fminf(fmaxf(0.1f * X, -10.0f), 10.0f);
    } else if (idx < 1600 + 7680) {
        const int p = idx - 1600;              // h2-pair index
        int rel, kind;
        if (p < 2048)      { kind = 0; rel = p; }
        else if (p < 4096) { kind = 1; rel = p - 2048; }
        else               { kind = 2; rel = p - 4096; }
        const int fi    = rel >> 8;
        const int lane2 = (rel >> 2) & 63;
        const int j     = (rel & 3) * 2;
        const int m     = (fi >> 1) * 16 + (lane2 & 15);
        const int k     = (fi & 1) * 32 + ((j & 4) ? 16 : 0)
                        + (lane2 >> 4) * 4 + (j & 3);
        float v0, v1;
        if (kind == 0) {
            v0 = W_down[k * DIM + m];           v1 = W_down[(k + 1) * DIM + m];
        } else if (kind == 1) {
            v0 = 0.04f * W_drift[k * DIM + m];  v1 = 0.04f * W_drift[(k + 1) * DIM + m];
        } else {
            v0 = (m < HID) ? W1[k * HID + m] : 0.0f;
            v1 = (m < HID) ? W1[(k + 1) * HID + m] : 0.0f;
        }
        *(h2*)(wpre + p * 2) = __builtin_amdgcn_cvt_pkrtz(v0, v1);
    } else if (idx < 9280 + 112) {
        const int i = idx - 9280;
        b1p[i] = (i < HID) ? b1[i] : 0.0f;      // padded to 112
    } else if (idx < 9392 + 112) {
        const int i = idx - 9392;
        w2p[i] = (i < HID) ? W2[i] : 0.0f;      // padded to 112
    }
}

union frag_u { h2 p[4]; f16x8 v; };

// ======================= PRE path (round-5 structure + pk_fma) =======================
// One block = 256 threads = 4 waves; each wave owns 16 batch rows.
// State kept TRANSPOSED (out^T). mfma_f32_16x16x32_f16 stacked-halves K layout
// (VERIFIED round 2). LDS = noise only (6.4 KB); weights read straight from
// the preconverted global buffer (L2-resident); dt*b_drift bias in registers.
// Round-8: eltwise uses v_pk_fma_f32 (issue-bound diagnosis: VALU = 54% of
// issue, scalar lowering of the f32x2 builtins).
__global__ __launch_bounds__(256, 4) void sdenet_fused_pre(
    const float* __restrict__ x,      const float* __restrict__ noise_g,
    const _Float16* __restrict__ wpre,
    const float* __restrict__ b_down, const float* __restrict__ b_drift,
    const float* __restrict__ b1p,    const float* __restrict__ w2p,
    const float* __restrict__ b2,
    float* __restrict__ out, int batch)
{
    __shared__ float noise_lds[DEPTH * DIM];   // 6400 B (the ONLY LDS)

    const int tid  = threadIdx.x;
    const int wave = tid >> 6;
    const int lane = tid & 63;
    const int r    = lane & 15;        // batch row within wave tile (B/C col)
    const int g    = lane >> 4;        // 16-lane group 0..3
    const int row  = blockIdx.x * 64 + wave * 16 + r;
    const int fbase = lane * 8;        // per-lane fragment offset (halves)
    const float dt = 0.04f;

    // noise -> LDS (400 float4s)
    {
        const float4* src = (const float4*)noise_g;
        float4* dst = (float4*)noise_lds;
        dst[tid] = src[tid];
        if (tid < 144) dst[tid + 256] = src[tid + 256];
    }
    // prefetch x (overlaps the LDS-write drain)
    float4 xlo[2], xhi[2];
    #pragma unroll
    for (int kt = 0; kt < 2; ++kt) {
        xlo[kt] = *(const float4*)(x + row * DIM + kt * 32 + g * 4);
        xhi[kt] = *(const float4*)(x + row * DIM + kt * 32 + 16 + g * 4);
    }
    __syncthreads();

    // ---------- initial: out0^T = W_down^T @ x^T + b_down ----------
    f16x8 bfrag[2];
    #pragma unroll
    for (int kt = 0; kt < 2; ++kt) {
        frag_u u;
        u.p[0] = __builtin_amdgcn_cvt_pkrtz(xlo[kt].x, xlo[kt].y);
        u.p[1] = __builtin_amdgcn_cvt_pkrtz(xlo[kt].z, xlo[kt].w);
        u.p[2] = __builtin_amdgcn_cvt_pkrtz(xhi[kt].x, xhi[kt].y);
        u.p[3] = __builtin_amdgcn_cvt_pkrtz(xhi[kt].z, xhi[kt].w);
        bfrag[kt] = u.v;
    }

    f32x2 out2[4][2];   // master fp32 state, C/D layout (dim = Mt*16 + 4g + reg)
    #pragma unroll
    for (int Mt = 0; Mt < 4; ++Mt) {
        f32x4 acc = *(const f32x4*)(b_down + Mt * 16 + g * 4);
        #pragma unroll
        for (int kt = 0; kt < 2; ++kt)
            acc = __builtin_amdgcn_mfma_f32_16x16x32_f16(
                *(const f16x8*)(wpre + (Mt * 2 + kt) * 512 + fbase),
                bfrag[kt], acc, 0, 0, 0);
        out2[Mt][0][0] = acc[0]; out2[Mt][0][1] = acc[1];
        out2[Mt][1][0] = acc[2]; out2[Mt][1][1] = acc[3];
    }

    // refresh B fragments from state: 8 packed RTZ converts
    auto refresh = [&]() {
        #pragma unroll
        for (int kt = 0; kt < 2; ++kt) {
            frag_u u;
            u.p[0] = __builtin_amdgcn_cvt_pkrtz(out2[2*kt  ][0][0], out2[2*kt  ][0][1]);
            u.p[1] = __builtin_amdgcn_cvt_pkrtz(out2[2*kt  ][1][0], out2[2*kt  ][1][1]);
            u.p[2] = __builtin_amdgcn_cvt_pkrtz(out2[2*kt+1][0][0], out2[2*kt+1][0][1]);
            u.p[3] = __builtin_amdgcn_cvt_pkrtz(out2[2*kt+1][1][0], out2[2*kt+1][1][1]);
            bfrag[kt] = u.v;
        }
    };
    refresh();

    // ---------- head: logit = relu(out0@W1+b1)@W2 + b2 (padded, no masks) ----------
    const _Float16* w1pre = wpre + 8192;
    float partial = 0.0f;
    #pragma unroll
    for (int Mt = 0; Mt < 7; ++Mt) {          // HID padded 100 -> 112
        f32x4 acc = *(const f32x4*)(b1p + Mt * 16 + g * 4);
        #pragma unroll
        for (int kt = 0; kt < 2; ++kt)
            acc = __builtin_amdgcn_mfma_f32_16x16x32_f16(
                *(const f16x8*)(w1pre + (Mt * 2 + kt) * 512 + fbase),
                bfrag[kt], acc, 0, 0, 0);
        #pragma unroll
        for (int reg = 0; reg < 4; ++reg)
            partial += fmaxf(acc[reg], 0.0f) * w2p[Mt * 16 + g * 4 + reg];
    }
    partial += __shfl_xor(partial, 16);
    partial += __shfl_xor(partial, 32);
    const float logit = partial + b2[0];
    const float scale = 0.5f * (1.0f / (1.0f + expf(-logit)))
                      * powf(0.04f, 1.0f / 1.8f);
    const f32x2 scale2 = { scale, scale };
    const f32x2 c104   = { 1.04f, 1.04f };
    const f32x2 zero2  = { 0.0f, 0.0f };

    // ---------- persistent dt-scaled drift fragments + dt*bias (registers) ----------
    f16x8 aWd[4][2];
    #pragma unroll
    for (int Mt = 0; Mt < 4; ++Mt)
        #pragma unroll
        for (int kt = 0; kt < 2; ++kt)
            aWd[Mt][kt] = *(const f16x8*)(wpre + 4096 + (Mt * 2 + kt) * 512 + fbase);

    f32x4 biasd[4];
    #pragma unroll
    for (int Mt = 0; Mt < 4; ++Mt) {
        f32x4 b = *(const f32x4*)(b_drift + Mt * 16 + g * 4);
        biasd[Mt][0] = b[0] * dt; biasd[Mt][1] = b[1] * dt;
        biasd[Mt][2] = b[2] * dt; biasd[Mt][3] = b[3] * dt;
    }

    // ---------- 25 SDE steps, all in registers ----------
    #pragma unroll
    for (int t = 0; t < DEPTH; ++t) {
        f32x4 nz[4];   // same-address broadcasts within each 16-lane group
        #pragma unroll
        for (int Mt = 0; Mt < 4; ++Mt)
            nz[Mt] = *(const f32x4*)(noise_lds + t * DIM + Mt * 16 + g * 4);

        f32x4 acc[4];
        #pragma unroll
        for (int Mt = 0; Mt < 4; ++Mt) {
            acc[Mt] = __builtin_amdgcn_mfma_f32_16x16x32_f16(
                aWd[Mt][0], bfrag[0], biasd[Mt], 0, 0, 0);
            acc[Mt] = __builtin_amdgcn_mfma_f32_16x16x32_f16(
                aWd[Mt][1], bfrag[1], acc[Mt], 0, 0, 0);
        }
        // out = pk_fma(scale, nz, pk_fma(out, 1.04, relu(acc)))  [v_pk_fma_f32]
        #pragma unroll
        for (int Mt = 0; Mt < 4; ++Mt) {
            #pragma unroll
            for (int h = 0; h < 2; ++h) {
                f32x2 a2 = { acc[Mt][2*h], acc[Mt][2*h+1] };
                f32x2 n2 = { nz[Mt][2*h],  nz[Mt][2*h+1] };
                f32x2 rel = __builtin_elementwise_max(a2, zero2);
                out2[Mt][h] = pk_fma(scale2, n2, pk_fma(out2[Mt][h], c104, rel));
            }
        }
        refresh();
    }

    // ---- final drift (undo dt scaling: relu(z) = relu(dt*z)*25) + stores ----
    const long long out2_off = (long long)batch * DIM;
    #pragma unroll
    for (int Mt = 0; Mt < 4; ++Mt) {
        f32x4 acc = __builtin_amdgcn_mfma_f32_16x16x32_f16(
            aWd[Mt][0], bfrag[0], biasd[Mt], 0, 0, 0);
        acc = __builtin_amdgcn_mfma_f32_16x16x32_f16(
            aWd[Mt][1], bfrag[1], acc, 0, 0, 0);
        float o0 = out2[Mt][0][0], o1 = out2[Mt][0][1];
        float o2 = out2[Mt][1][0], o3 = out2[Mt][1][1];
        float4 dv, ov;
        dv.x = fmaf(fmaxf(acc[0], 0.0f), 25.0f, o0);
        dv.y = fmaf(fmaxf(acc[1], 0.0f), 25.0f, o1);
        dv.z = fmaf(fmaxf(acc[2], 0.0f), 25.0f, o2);
        dv.w = fmaf(fmaxf(acc[3], 0.0f), 25.0f, o3);
        ov.x = o0; ov.y = o1; ov.z = o2; ov.w = o3;
        *(float4*)(out + (long long)row * DIM + Mt * 16 + g * 4) = dv;
        *(float4*)(out + out2_off + (long long)row * DIM + Mt * 16 + g * 4) = ov;
    }
}

// ============== FALLBACK path (round-4 kernel, in-block staging) ==============
__global__ __launch_bounds__(256, 4) void sdenet_fused_fb(
    const float* __restrict__ x,      const float* __restrict__ noise_g,
    const float* __restrict__ W_down, const float* __restrict__ b_down,
    const float* __restrict__ W_drift,const float* __restrict__ b_drift,
    const float* __restrict__ W1,     const float* __restrict__ b1,
    const float* __restrict__ W2,     const float* __restrict__ b2,
    float* __restrict__ out, int batch)
{
    __shared__ float    noise_lds[DEPTH * DIM];
    __shared__ float    bias_lds[DIM];
    __shared__ _Float16 wdown[4096];
    __shared__ _Float16 wdrift[4096];
    __shared__ _Float16 w1buf[7168];

    const int tid  = threadIdx.x;
    const int wave = tid >> 6;
    const int lane = tid & 63;
    const int r    = lane & 15;
    const int g    = lane >> 4;
    const int row  = blockIdx.x * 64 + wave * 16 + r;
    const int fbase = lane * 8;
    const float dt = 0.04f;

    {
        const float4* src = (const float4*)noise_g;
        float4* dst = (float4*)noise_lds;
        #pragma unroll
        for (int it = 0; it < 2; ++it) {
            int idx = tid + it * 256;
            if (idx < DEPTH * DIM / 4) dst[idx] = src[idx];
        }
    }
    if (tid < DIM) bias_lds[tid] = dt * b_drift[tid];

    for (int idx2 = tid; idx2 < 2048; idx2 += 256) {
        const int fi    = idx2 >> 8;
        const int lane2 = (idx2 >> 2) & 63;
        const int j     = (idx2 & 3) * 2;
        const int m     = (fi >> 1) * 16 + (lane2 & 15);
        const int k     = (fi & 1) * 32 + ((j & 4) ? 16 : 0)
                        + (lane2 >> 4) * 4 + (j & 3);
        *(h2*)(wdown + idx2 * 2) =
            __builtin_amdgcn_cvt_pkrtz(W_down[k * DIM + m],
                                       W_down[(k + 1) * DIM + m]);
        *(h2*)(wdrift + idx2 * 2) =
            __builtin_amdgcn_cvt_pkrtz(dt * W_drift[k * DIM + m],
                                       dt * W_drift[(k + 1) * DIM + m]);
    }
    for (int idx2 = tid; idx2 < 3584; idx2 += 256) {
        const int fi    = idx2 >> 8;
        const int lane2 = (idx2 >> 2) & 63;
        const int j     = (idx2 & 3) * 2;
        const int n     = (fi >> 1) * 16 + (lane2 & 15);
        const int k     = (fi & 1) * 32 + ((j & 4) ? 16 : 0)
                        + (lane2 >> 4) * 4 + (j & 3);
        const float v0 = (n < HID) ? W1[k * HID + n] : 0.0f;
        const float v1 = (n < HID) ? W1[(k + 1) * HID + n] : 0.0f;
        *(h2*)(w1buf + idx2 * 2) = __builtin_amdgcn_cvt_pkrtz(v0, v1);
    }

    float4 xlo[2], xhi[2];
    #pragma unroll
    for (int kt = 0; kt < 2; ++kt) {
        xlo[kt] = *(const float4*)(x + row * DIM + kt * 32 + g * 4);
        xhi[kt] = *(const float4*)(x + row * DIM + kt * 32 + 16 + g * 4);
    }
    __syncthreads();

    f16x8 bfrag[2];
    #pragma unroll
    for (int kt = 0; kt < 2; ++kt) {
        frag_u u;
        u.p[0] = __builtin_amdgcn_cvt_pkrtz(xlo[kt].x, xlo[kt].y);
        u.p[1] = __builtin_amdgcn_cvt_pkrtz(xlo[kt].z, xlo[kt].w);
        u.p[2] = __builtin_amdgcn_cvt_pkrtz(xhi[kt].x, xhi[kt].y);
        u.p[3] = __builtin_amdgcn_cvt_pkrtz(xhi[kt].z, xhi[kt].w);
        bfrag[kt] = u.v;
    }

    f32x2 out2[4][2];
    #pragma unroll
    for (int Mt = 0; Mt < 4; ++Mt) {
        f32x4 acc = *(const f32x4*)(b_down + Mt * 16 + g * 4);
        #pragma unroll
        for (int kt = 0; kt < 2; ++kt)
            acc = __builtin_amdgcn_mfma_f32_16x16x32_f16(
                *(const f16x8*)(wdown + (Mt * 2 + kt) * 512 + fbase),
                bfrag[kt], acc, 0, 0, 0);
        out2[Mt][0][0] = acc[0]; out2[Mt][0][1] = acc[1];
        out2[Mt][1][0] = acc[2]; out2[Mt][1][1] = acc[3];
    }

    auto refresh = [&]() {
        #pragma unroll
        for (int kt = 0; kt < 2; ++kt) {
            frag_u u;
            u.p[0] = __builtin_amdgcn_cvt_pkrtz(out2[2*kt  ][0][0], out2[2*kt  ][0][1]);
            u.p[1] = __builtin_amdgcn_cvt_pkrtz(out2[2*kt  ][1][0], out2[2*kt  ][1][1]);
            u.p[2] = __builtin_amdgcn_cvt_pkrtz(out2[2*kt+1][0][0], out2[2*kt+1][0][1]);
            u.p[3] = __builtin_amdgcn_cvt_pkrtz(out2[2*kt+1][1][0], out2[2*kt+1][1][1]);
            bfrag[kt] = u.v;
        }
    };
    refresh();

    float partial = 0.0f;
    #pragma unroll
    for (int Mt = 0; Mt < 7; ++Mt) {
        f32x4 acc;
        #pragma unroll
        for (int reg = 0; reg < 4; ++reg) {
            const int n = Mt * 16 + g * 4 + reg;
            acc[reg] = (n < HID) ? b1[n] : 0.0f;
        }
        #pragma unroll
        for (int kt = 0; kt < 2; ++kt)
            acc = __builtin_amdgcn_mfma_f32_16x16x32_f16(
                *(const f16x8*)(w1buf + (Mt * 2 + kt) * 512 + fbase),
                bfrag[kt], acc, 0, 0, 0);
        #pragma unroll
        for (int reg = 0; reg < 4; ++reg) {
            const int n = Mt * 16 + g * 4 + reg;
            if (n < HID) partial += fmaxf(acc[reg], 0.0f) * W2[n];
        }
    }
    partial += __shfl_xor(partial, 16);
    partial += __shfl_xor(partial, 32);
    const float logit = partial + b2[0];
    const float scale = 0.5f * (1.0f / (1.0f + expf(-logit)))
                      * powf(0.04f, 1.0f / 1.8f);
    const f32x2 scale2 = { scale, scale };
    const f32x2 c104   = { 1.04f, 1.04f };
    const f32x2 zero2  = { 0.0f, 0.0f };

    f16x8 aWd[4][2];
    #pragma unroll
    for (int Mt = 0; Mt < 4; ++Mt)
        #pragma unroll
        for (int kt = 0; kt < 2; ++kt)
            aWd[Mt][kt] = *(const f16x8*)(wdrift + (Mt * 2 + kt) * 512 + fbase);

    #pragma unroll
    for (int t = 0; t < DEPTH; ++t) {
        f32x4 nz[4];
        #pragma unroll
        for (int Mt = 0; Mt < 4; ++Mt)
            nz[Mt] = *(const f32x4*)(noise_lds + t * DIM + Mt * 16 + g * 4);

        f32x4 acc[4];
        #pragma unroll
        for (int Mt = 0; Mt < 4; ++Mt) {
            acc[Mt] = *(const f32x4*)(bias_lds + Mt * 16 + g * 4);
            acc[Mt] = __builtin_amdgcn_mfma_f32_16x16x32_f16(
                aWd[Mt][0], bfrag[0], acc[Mt], 0, 0, 0);
            acc[Mt] = __builtin_amdgcn_mfma_f32_16x16x32_f16(
                aWd[Mt][1], bfrag[1], acc[Mt], 0, 0, 0);
        }
        #pragma unroll
        for (int Mt = 0; Mt < 4; ++Mt) {
            #pragma unroll
            for (int h = 0; h < 2; ++h) {
                f32x2 a2 = { acc[Mt][2*h], acc[Mt][2*h+1] };
                f32x2 n2 = { nz[Mt][2*h],  nz[Mt][2*h+1] };
                f32x2 rel = __builtin_elementwise_max(a2, zero2);
                out2[Mt][h] = pk_fma(scale2, n2, pk_fma(out2[Mt][h], c104, rel));
            }
        }
        refresh();
    }

    const long long out2_off = (long long)batch * DIM;
    #pragma unroll
    for (int Mt = 0; Mt < 4; ++Mt) {
        f32x4 acc = *(const f32x4*)(bias_lds + Mt * 16 + g * 4);
        acc = __builtin_amdgcn_mfma_f32_16x16x32_f16(
            aWd[Mt][0], bfrag[0], acc, 0, 0, 0);
        acc = __builtin_amdgcn_mfma_f32_16x16x32_f16(
            aWd[Mt][1], bfrag[1], acc, 0, 0, 0);
        float o0 = out2[Mt][0][0], o1 = out2[Mt][0][1];
        float o2 = out2[Mt][1][0], o3 = out2[Mt][1][1];
        float4 dv, ov;
        dv.x = fmaf(fmaxf(acc[0], 0.0f), 25.0f, o0);
        dv.y = fmaf(fmaxf(acc[1], 0.0f), 25.0f, o1);
        dv.z = fmaf(fmaxf(acc[2], 0.0f), 25.0f, o2);
        dv.w = fmaf(fmaxf(acc[3], 0.0f), 25.0f, o3);
        ov.x = o0; ov.y = o1; ov.z = o2; ov.w = o3;
        *(float4*)(out + (long long)row * DIM + Mt * 16 + g * 4) = dv;
        *(float4*)(out + out2_off + (long long)row * DIM + Mt * 16 + g * 4) = ov;
    }
}

extern "C" void kernel_launch(void* const* d_in, const int* in_sizes, int n_in,
                              void* d_out, int out_size, void* d_ws, size_t ws_size,
                              hipStream_t stream) {
    const float* x       = (const float*)d_in[0];
    const float* u_raw   = (const float*)d_in[1];
    const float* w_raw   = (const float*)d_in[2];
    const float* W_down  = (const float*)d_in[3];
    const float* b_down  = (const float*)d_in[4];
    const float* W_drift = (const float*)d_in[5];
    const float* b_drift = (const float*)d_in[6];
    const float* W1      = (const float*)d_in[7];
    const float* b1      = (const float*)d_in[8];
    const float* W2      = (const float*)d_in[9];
    const float* b2      = (const float*)d_in[10];
    float* out   = (float*)d_out;

    // workspace layout: [0,6400) noise f32 | [6400,37120) wpre f16 |
    //                   [37120,37568) b1p  | [37568,38016) w2p
    float*     noise = (float*)d_ws;
    _Float16*  wpre  = (_Float16*)((char*)d_ws + 6400);
    float*     b1p   = (float*)((char*)d_ws + 37120);
    float*     w2p   = (float*)((char*)d_ws + 37568);

    const int batch = in_sizes[0] / DIM;       // 262144

    if (ws_size >= 38016) {
        prep_kernel<<<38, 256, 0, stream>>>(u_raw, w_raw, W_down, W_drift,
                                            W1, b1, W2, noise, wpre, b1p, w2p);
        sdenet_fused_pre<<<batch / 64, 256, 0, stream>>>(
            x, noise, wpre, b_down, b_drift, b1p, w2p, b2, out, batch);
    } else {
        prep_kernel<<<7, 256, 0, stream>>>(u_raw, w_raw, W_down, W_drift,
                                           W1, b1, W2, noise,
                                           (_Float16*)noise, noise, noise);
        sdenet_fused_fb<<<batch / 64, 256, 0, stream>>>(
            x, noise, W_down, b_down, W_drift, b_drift,
            W1, b1, W2, b2, out, batch);
    }
}